// Round 25
// baseline (510.102 us; speedup 1.0000x reference)
//
#include <hip/hip_runtime.h>
#include <hip/hip_bf16.h>
#include <cstdint>
#include <cstddef>

#define T_LEN 4096
#define TP 4104      // emb rows: pixel t at row t+2; rows 0,1 and 4098..4103 zero
#define TPX 4120     // XF rows: pixel t at row t+10; rows 0..9 and 4106..4119 zero
#define BATCH 32
#define NMELS 80
#define HID 128
#define W_WORDS 64
#define D_MAX 100
#define WHALO 68
#define DHALO 120

typedef __attribute__((ext_vector_type(4))) float f32x4;
typedef __attribute__((ext_vector_type(8))) short short8;

static __device__ __forceinline__ unsigned short f2bf(float f) {
    __hip_bfloat16 h = __float2bfloat16(f);
    return *reinterpret_cast<unsigned short*>(&h);
}

// async global->LDS DMA, 16B per lane; dest = wave-uniform base + lane*16
typedef const __attribute__((address_space(1))) unsigned int* as1_u32p;
typedef __attribute__((address_space(3))) unsigned int* as3_u32p;
static __device__ __forceinline__ void gload16(const void* g, void* l) {
    __builtin_amdgcn_global_load_lds((as1_u32p)(uintptr_t)g, (as3_u32p)(uintptr_t)l, 16, 0, 0);
}

// ---------- pack weights into MFMA A-fragment order ----------
template <int CIN, int CC, int TAPS>
__global__ __launch_bounds__(256) void pack_w_kernel(const float* __restrict__ w,
                                                     __hip_bfloat16* __restrict__ wf) {
    int idx = blockIdx.x * 256 + threadIdx.x;
    int r = idx;
    int j = r & 7; r >>= 3;
    int lane = r & 63; r >>= 6;
    int mi = r & 7; r >>= 3;
    int tap = r % TAPS;
    int cc = r / TAPS;
    if (cc >= CC) return;
    int co = mi * 16 + (lane & 15);
    int ci = cc * 32 + (lane >> 4) * 8 + j;
    float v = (ci < CIN) ? w[(co * CIN + ci) * TAPS + tap] : 0.f;
    wf[idx] = __float2bfloat16(v);
}

// ---------- cast features: tiled LDS transpose (b,80,t) fp32 -> XF (b,TPX,96) bf16 ----------
__global__ __launch_bounds__(256) void cast_feat_kernel(const float* __restrict__ f,
                                                        __hip_bfloat16* __restrict__ xf) {
    __shared__ unsigned short lds[64 * 100];
    const int tid = threadIdx.x;
    const int t0 = blockIdx.x * 64;
    const int b = blockIdx.y;

#pragma unroll
    for (int k = 0; k < 6; k++) {
        int idx = tid + k * 256;
        int f4 = idx & 15;
        int c = idx >> 4;
        float4 v = make_float4(0.f, 0.f, 0.f, 0.f);
        if (c < NMELS)
            v = *(const float4*)(f + ((size_t)b * NMELS + c) * T_LEN + t0 + f4 * 4);
        lds[(f4 * 4 + 0) * 100 + c] = f2bf(v.x);
        lds[(f4 * 4 + 1) * 100 + c] = f2bf(v.y);
        lds[(f4 * 4 + 2) * 100 + c] = f2bf(v.z);
        lds[(f4 * 4 + 3) * 100 + c] = f2bf(v.w);
    }
    __syncthreads();
    unsigned short* xp = (unsigned short*)xf;
#pragma unroll
    for (int k = 0; k < 6; k++) {
        int idx = tid + k * 256;
        int tl = idx / 24;
        int cq = idx - tl * 24;
        ushort4 o;
        o.x = lds[tl * 100 + cq * 4 + 0];
        o.y = lds[tl * 100 + cq * 4 + 1];
        o.z = lds[tl * 100 + cq * 4 + 2];
        o.w = lds[tl * 100 + cq * 4 + 3];
        *(ushort4*)(xp + ((size_t)b * TPX + t0 + tl + 10) * 96 + cq * 4) = o;
    }
}

// ---------- zero the 24 halo t-rows of XF (rows 0..9 and 4106..4119) ----------
__global__ void zero_xf_halo_kernel(__hip_bfloat16* __restrict__ p) {
    int r = blockIdx.x;            // 0..23
    int b = blockIdx.y;
    int row = (r < 10) ? r : 4096 + r; // 0..9, 4106..4119
    ((unsigned short*)p)[((size_t)b * TPX + row) * 96 + threadIdx.x] = 0;
}

// ---------- zero halo strips of P5 (b,68,120,128) ----------
__global__ __launch_bounds__(256) void zero_p5_halo_kernel(__hip_bfloat16* __restrict__ p) {
    int idx = blockIdx.x * 256 + threadIdx.x; // 32*1760*64
    if (idx >= 32 * 1760 * 64) return;
    int c2 = (idx & 63) * 2;
    int cell = idx >> 6;
    int b = cell / 1760;
    int cl = cell - b * 1760;
    int row, col;
    if (cl < 480) {
        int rr = cl / 120;
        row = (rr < 2) ? rr : 64 + rr;
        col = cl - rr * 120;
    } else {
        int cl2 = cl - 480;
        row = 2 + cl2 / 20;
        int q = cl2 % 20;
        col = (q < 2) ? q : 100 + q;
    }
    *(unsigned int*)((unsigned short*)p + (((size_t)b * WHALO + row) * DHALO + col) * 128 + c2) = 0u;
}

// ---------- FUSED conv1d x3: XF -> (h1,h2 in LDS) -> emb (round-15 form, kept) ----------
__global__ __launch_bounds__(256, 3) void conv1d_fused_kernel(
    const __hip_bfloat16* __restrict__ xf, const __hip_bfloat16* __restrict__ wf1,
    const float* __restrict__ b1, const __hip_bfloat16* __restrict__ wf2,
    const float* __restrict__ b2, const __hip_bfloat16* __restrict__ wf3,
    const float* __restrict__ b3, __hip_bfloat16* __restrict__ emb) {
    __shared__ short lds[(1344 + 1344) * 8];
    short* A = lds;              // XF, then h2
    short* H1 = lds + 1344 * 8;  // h1
    const int tid = threadIdx.x;
    const int lane = tid & 63;
    const int wid = tid >> 6;    // co-quarter (32 co)
    const int pix0 = blockIdx.x * 64;
    const int b = blockIdx.y;

    const short* xfp = (const short*)xf;
#pragma unroll
    for (int it = 0; it < 4; it++) {
        int cbase = (it * 4 + wid) * 64;
        if (cbase < 1008) {
            int cell = cbase + lane;
            int jg = cell / 84;
            int col = cell - jg * 84;
            if (jg > 11) { jg = 11; col = 83; } // pad lanes: clamp SOURCE (dest = pad cell)
            const short* g = xfp + ((size_t)(b * TPX + pix0 + col)) * 96 + jg * 8;
            gload16(g, A + (size_t)cbase * 8);
        }
    }
    __syncthreads(); // drain DMA

    const short* w1p = (const short*)wf1;
    const short* w2p = (const short*)wf2;
    const short* w3p = (const short*)wf3;

    f32x4 acc[5][2];

    // ---- layer 1: XF(A) -> h1(H1), relu ----
#pragma unroll
    for (int n = 0; n < 5; n++)
#pragma unroll
        for (int mi = 0; mi < 2; mi++) acc[n][mi] = (f32x4)0.f;
#pragma unroll 1
    for (int cc = 0; cc < 3; cc++) {
#pragma unroll
        for (int th = 0; th < 5; th++) {
            const short* wptr = w1p + ((cc * 5 + th) * 8 + wid * 2) * 512 + lane * 8;
            short8 wfr0 = *(const short8*)wptr;
            short8 wfr1 = *(const short8*)(wptr + 512);
            short8 xfr[5];
#pragma unroll
            for (int n = 0; n < 5; n++)
                xfr[n] = *(const short8*)&A[((cc * 4 + (lane >> 4)) * 84 +
                                             (n * 16 + (lane & 15) + th)) * 8];
#pragma unroll
            for (int n = 0; n < 5; n++) {
                acc[n][0] = __builtin_amdgcn_mfma_f32_16x16x32_bf16(wfr0, xfr[n], acc[n][0], 0, 0, 0);
                acc[n][1] = __builtin_amdgcn_mfma_f32_16x16x32_bf16(wfr1, xfr[n], acc[n][1], 0, 0, 0);
            }
        }
    }
#pragma unroll
    for (int mi = 0; mi < 2; mi++) {
        const float4 bv = *(const float4*)(b1 + wid * 32 + mi * 16 + (lane >> 4) * 4);
        const int jgI = wid * 4 + mi * 2 + ((lane >> 4) >> 1);
#pragma unroll
        for (int n = 0; n < 5; n++) {
            f32x4 a = acc[n][mi];
            const int col = n * 16 + (lane & 15) + 2;
            const int px = pix0 + col - 10;
            const bool inseq = ((unsigned)px < (unsigned)T_LEN);
            ushort4 o;
            o.x = inseq ? f2bf(fmaxf(a[0] + bv.x, 0.f)) : (unsigned short)0;
            o.y = inseq ? f2bf(fmaxf(a[1] + bv.y, 0.f)) : (unsigned short)0;
            o.z = inseq ? f2bf(fmaxf(a[2] + bv.z, 0.f)) : (unsigned short)0;
            o.w = inseq ? f2bf(fmaxf(a[3] + bv.w, 0.f)) : (unsigned short)0;
            *(ushort4*)&H1[(jgI * 84 + col) * 8 + ((lane >> 4) & 1) * 4] = o;
        }
    }
    __syncthreads(); // h1 published; XF reads done (A reusable)

    // ---- layer 2: h1(H1) -> h2(A), relu ----
#pragma unroll
    for (int n = 0; n < 5; n++)
#pragma unroll
        for (int mi = 0; mi < 2; mi++) acc[n][mi] = (f32x4)0.f;
#pragma unroll 1
    for (int cc = 0; cc < 4; cc++) {
#pragma unroll
        for (int th = 0; th < 5; th++) {
            const short* wptr = w2p + ((cc * 5 + th) * 8 + wid * 2) * 512 + lane * 8;
            short8 wfr0 = *(const short8*)wptr;
            short8 wfr1 = *(const short8*)(wptr + 512);
            short8 xfr[5];
#pragma unroll
            for (int n = 0; n < 5; n++)
                xfr[n] = *(const short8*)&H1[((cc * 4 + (lane >> 4)) * 84 +
                                              (n * 16 + (lane & 15) + th)) * 8];
#pragma unroll
            for (int n = 0; n < 5; n++) {
                acc[n][0] = __builtin_amdgcn_mfma_f32_16x16x32_bf16(wfr0, xfr[n], acc[n][0], 0, 0, 0);
                acc[n][1] = __builtin_amdgcn_mfma_f32_16x16x32_bf16(wfr1, xfr[n], acc[n][1], 0, 0, 0);
            }
        }
    }
#pragma unroll
    for (int mi = 0; mi < 2; mi++) {
        const float4 bv = *(const float4*)(b2 + wid * 32 + mi * 16 + (lane >> 4) * 4);
        const int jgI = wid * 4 + mi * 2 + ((lane >> 4) >> 1);
#pragma unroll
        for (int n = 0; n < 5; n++) {
            f32x4 a = acc[n][mi];
            const int col = n * 16 + (lane & 15) + 2;
            const int px = pix0 + col - 10;
            const bool inseq = ((unsigned)px < (unsigned)T_LEN);
            ushort4 o;
            o.x = inseq ? f2bf(fmaxf(a[0] + bv.x, 0.f)) : (unsigned short)0;
            o.y = inseq ? f2bf(fmaxf(a[1] + bv.y, 0.f)) : (unsigned short)0;
            o.z = inseq ? f2bf(fmaxf(a[2] + bv.z, 0.f)) : (unsigned short)0;
            o.w = inseq ? f2bf(fmaxf(a[3] + bv.w, 0.f)) : (unsigned short)0;
            *(ushort4*)&A[(jgI * 84 + col) * 8 + ((lane >> 4) & 1) * 4] = o;
        }
    }
    __syncthreads(); // h2 published

    // ---- layer 3: h2(A) -> emb global (no relu), 4 frags (64 px exact) ----
#pragma unroll
    for (int n = 0; n < 4; n++)
#pragma unroll
        for (int mi = 0; mi < 2; mi++) acc[n][mi] = (f32x4)0.f;
#pragma unroll 1
    for (int cc = 0; cc < 4; cc++) {
#pragma unroll
        for (int th = 0; th < 5; th++) {
            const short* wptr = w3p + ((cc * 5 + th) * 8 + wid * 2) * 512 + lane * 8;
            short8 wfr0 = *(const short8*)wptr;
            short8 wfr1 = *(const short8*)(wptr + 512);
            short8 xfr[4];
#pragma unroll
            for (int n = 0; n < 4; n++)
                xfr[n] = *(const short8*)&A[((cc * 4 + (lane >> 4)) * 84 +
                                             (n * 16 + (lane & 15) + th + 8)) * 8];
#pragma unroll
            for (int n = 0; n < 4; n++) {
                acc[n][0] = __builtin_amdgcn_mfma_f32_16x16x32_bf16(wfr0, xfr[n], acc[n][0], 0, 0, 0);
                acc[n][1] = __builtin_amdgcn_mfma_f32_16x16x32_bf16(wfr1, xfr[n], acc[n][1], 0, 0, 0);
            }
        }
    }
    unsigned short* ep = (unsigned short*)emb;
#pragma unroll
    for (int mi = 0; mi < 2; mi++) {
        const float4 bv = *(const float4*)(b3 + wid * 32 + mi * 16 + (lane >> 4) * 4);
#pragma unroll
        for (int n = 0; n < 4; n++) {
            f32x4 a = acc[n][mi];
            ushort4 o;
            o.x = f2bf(a[0] + bv.x);
            o.y = f2bf(a[1] + bv.y);
            o.z = f2bf(a[2] + bv.z);
            o.w = f2bf(a[3] + bv.w);
            const int px = pix0 + n * 16 + (lane & 15);
            *(ushort4*)(ep + ((size_t)(b * TP + px + 2)) * 128 + wid * 32 + mi * 16 +
                        (lane >> 4) * 4) = o;
        }
    }
}

// ---------- conv2d MFMA: r22 form + 64-ci slab with CONSTANT addressing ----------
// LDS [jg(8)][row(8)][col(68)] 16B cells = 4352 cells = 68 whole-wave transfers exact
// (69,632 B). Stage 64 ci per barrier-pair -> 3 barriers/block (was 7). Addressing uses
// only constant divisors (544, 68) — identical register shape to r22 (r16/r19 spilled
// from dtile-dependent geometry, not the slab). Occupancy reg-capped at 2 blocks/CU;
// 2 x 69.6 KB < 160 KB LDS, so unchanged. dtile1 stages cols 52..67 unread (as r22).
// OMODE 1: bf16 halo plane out. OMODE 2: fused einsum -> fp32 partials xep[b,co,w,2].
template <bool GATHER, bool RELU, int OMODE>
__global__ __launch_bounds__(512, 4) void conv2d_lds_kernel(const __hip_bfloat16* __restrict__ in,
                                                            const int* __restrict__ wb,
                                                            const __hip_bfloat16* __restrict__ wf,
                                                            const float* __restrict__ bias,
                                                            const __hip_bfloat16* __restrict__ zp,
                                                            const float* __restrict__ lw,
                                                            float* __restrict__ xep,
                                                            __hip_bfloat16* __restrict__ outp) {
    __shared__ short lds[8 * 8 * 68 * 8]; // 69,632 B; 4352 cells = 68*64 exact
    __shared__ int2 s_sd[8];
    const int tid = threadIdx.x;
    const int lane = tid & 63;
    const int wid = tid >> 6;
    const int wrow = wid & 3;
    const int cohalf = wid >> 2;
    const int w0 = (blockIdx.x & 15) * 4;
    const int dtile = blockIdx.x >> 4;
    const int D0 = dtile * 64;
    const int ntlim = dtile ? 3 : 4;
    const int b = blockIdx.y;
    const int w = w0 + wrow;

    if (GATHER && tid < 8) {
        int wg = w0 + tid - 2;
        int s = 0, du = 0;
        if (wg >= 0 && wg < 64) {
            s = wb[(b * 64 + wg) * 2];
            du = wb[(b * 64 + wg) * 2 + 1] - s;
            if (du > D_MAX) du = D_MAX;
        }
        s_sd[tid] = make_int2(s, du);
    }
    __syncthreads(); // s_sd visible before staging

    const short* inp = (const short*)in;
    const short* wfp = (const short*)wf;

    // stage one 64-ci slab (ccp = 0 or 1): ci = ccp*64 + jg*8, jg = 0..7
    auto stage = [&](int ccp) {
#pragma unroll
        for (int it = 0; it < 9; it++) {
            int cbase = (it * 8 + wid) * 64;
            if (cbase < 4352) {
                int cell = cbase + lane;
                int jg = cell / 544;
                int rem = cell - jg * 544;
                int row = rem / 68;
                int col = rem - row * 68;
                const short* g;
                if (GATHER) {
                    int d = D0 + col - 2;
                    int2 sd = s_sd[row];
                    if ((unsigned)d < (unsigned)sd.y)
                        g = inp + ((size_t)(b * TP + 2 + sd.x + d)) * 128 + ccp * 64 + jg * 8;
                    else
                        g = (const short*)zp;
                } else {
                    g = inp + ((size_t)((b * WHALO + w0 + row) * DHALO + D0 + col)) * 128 +
                        ccp * 64 + jg * 8;
                }
                gload16(g, &lds[0] + (size_t)cbase * 8);
            }
        }
    };

    f32x4 acc[4][4];
#pragma unroll
    for (int n = 0; n < 4; n++)
#pragma unroll
        for (int mi = 0; mi < 4; mi++) acc[n][mi] = (f32x4)0.f;

#pragma unroll 1
    for (int ccp = 0; ccp < 2; ccp++) {
        if (ccp) __syncthreads(); // readers of lds done
        stage(ccp);               // async DMA issue
        __syncthreads();          // drain -> slab ready
#pragma unroll 1
        for (int cch = 0; cch < 2; cch++) {
            const int cc = ccp * 2 + cch;
#pragma unroll 1
            for (int th = 0; th < 5; th++) {
#pragma unroll
                for (int tw = 0; tw < 5; tw++) {
                    const int tap = th * 5 + tw;
                    const short* wptr =
                        wfp + ((cc * 25 + tap) * 8 + cohalf * 4) * 512 + lane * 8;
                    short8 wfr[4];
#pragma unroll
                    for (int mi = 0; mi < 4; mi++) wfr[mi] = *(const short8*)(wptr + mi * 512);

                    short8 xfr[4];
#pragma unroll
                    for (int n = 0; n < 4; n++)
                        if (n < ntlim)
                            xfr[n] = *(const short8*)&lds[(((cch * 4 + (lane >> 4)) * 8 + wrow +
                                                            th) * 68 +
                                                           (tw + n * 16 + (lane & 15))) * 8];

#pragma unroll
                    for (int n = 0; n < 4; n++)
                        if (n < ntlim)
#pragma unroll
                            for (int mi = 0; mi < 4; mi++)
                                acc[n][mi] = __builtin_amdgcn_mfma_f32_16x16x32_bf16(
                                    wfr[mi], xfr[n], acc[n][mi], 0, 0, 0);
                }
            }
        }
    }

    if (OMODE == 1) {
        const int out_base = ((b * WHALO + w + 2) * DHALO + D0 + 2) * 128;
        unsigned short* outp16 = (unsigned short*)outp;
#pragma unroll
        for (int mi = 0; mi < 4; mi++) {
            const float4 bv = *(const float4*)(bias + cohalf * 64 + mi * 16 + (lane >> 4) * 4);
#pragma unroll
            for (int n = 0; n < 4; n++) {
                const int pix = n * 16 + (lane & 15);
                if (D0 + pix >= 100) continue;
                f32x4 a = acc[n][mi];
                float v0 = a[0] + bv.x, v1 = a[1] + bv.y, v2 = a[2] + bv.z, v3 = a[3] + bv.w;
                if (RELU) {
                    v0 = fmaxf(v0, 0.f); v1 = fmaxf(v1, 0.f);
                    v2 = fmaxf(v2, 0.f); v3 = fmaxf(v3, 0.f);
                }
                ushort4 o;
                o.x = f2bf(v0); o.y = f2bf(v1); o.z = f2bf(v2); o.w = f2bf(v3);
                *(ushort4*)(outp16 + out_base + pix * 128 + cohalf * 64 + mi * 16 +
                            (lane >> 4) * 4) = o;
            }
        }
    } else {
        float e[4][4];
#pragma unroll
        for (int mi = 0; mi < 4; mi++)
#pragma unroll
            for (int j = 0; j < 4; j++) e[mi][j] = 0.f;

#pragma unroll
        for (int mi = 0; mi < 4; mi++) {
            const float4 bv = *(const float4*)(bias + cohalf * 64 + mi * 16 + (lane >> 4) * 4);
#pragma unroll
            for (int n = 0; n < 4; n++) {
                const int pix = n * 16 + (lane & 15);
                if (D0 + pix >= 100) continue;
                const float lwv = lw[D0 + pix];
                f32x4 a = acc[n][mi];
                e[mi][0] += fmaxf(a[0] + bv.x, 0.f) * lwv;
                e[mi][1] += fmaxf(a[1] + bv.y, 0.f) * lwv;
                e[mi][2] += fmaxf(a[2] + bv.z, 0.f) * lwv;
                e[mi][3] += fmaxf(a[3] + bv.w, 0.f) * lwv;
            }
        }
#pragma unroll
        for (int mi = 0; mi < 4; mi++)
#pragma unroll
            for (int j = 0; j < 4; j++) {
                float v = e[mi][j];
                v += __shfl_xor(v, 1);
                v += __shfl_xor(v, 2);
                v += __shfl_xor(v, 4);
                v += __shfl_xor(v, 8);
                e[mi][j] = v;
            }
        if ((lane & 15) == 0) {
#pragma unroll
            for (int mi = 0; mi < 4; mi++)
#pragma unroll
                for (int j = 0; j < 4; j++) {
                    int co = cohalf * 64 + mi * 16 + (lane >> 4) * 4 + j;
                    xep[(((size_t)b * 128 + co) * 64 + w) * 2 + dtile] = e[mi][j];
                }
        }
    }
}

// ---------- final conv: XEp partials (b,128,64,2) -> out (b,64); ci-parallel ----------
__global__ __launch_bounds__(256) void conv6_kernel(const float* __restrict__ xep,
                                                    const float* __restrict__ lb,
                                                    const float* __restrict__ w6,
                                                    const float* __restrict__ b6,
                                                    float* __restrict__ out) {
    __shared__ float red[256];
    const int b = blockIdx.x;
    const int w = threadIdx.x & 63;
    const int cq = threadIdx.x >> 6; // 4 groups of 32 ci
    const float lb0 = lb[0];
    float partial = 0.f;
#pragma unroll 1
    for (int ci = cq * 32; ci < cq * 32 + 32; ci++) {
        const float* xr = xep + (((size_t)b * 128 + ci) * 64) * 2;
#pragma unroll
        for (int kh = 0; kh < 5; kh++) {
            int ww = w + kh - 2;
            if ((unsigned)ww < 64u) {
                float x = fmaxf(xr[ww * 2] + xr[ww * 2 + 1] + lb0, 0.f);
                partial += x * w6[ci * 25 + kh * 5 + 2];
            }
        }
    }
    red[threadIdx.x] = partial;
    __syncthreads();
    if (cq == 0)
        out[b * 64 + w] = red[w] + red[w + 64] + red[w + 128] + red[w + 192] + b6[0];
}

extern "C" void kernel_launch(void* const* d_in, const int* in_sizes, int n_in,
                              void* d_out, int out_size, void* d_ws, size_t ws_size,
                              hipStream_t stream) {
    const float* features = (const float*)d_in[0];
    const int* wbnd = (const int*)d_in[1];
    const float* w1 = (const float*)d_in[2];
    const float* b1 = (const float*)d_in[3];
    const float* w2 = (const float*)d_in[4];
    const float* b2 = (const float*)d_in[5];
    const float* w3 = (const float*)d_in[6];
    const float* b3 = (const float*)d_in[7];
    const float* w4 = (const float*)d_in[8];
    const float* b4 = (const float*)d_in[9];
    const float* w5 = (const float*)d_in[10];
    const float* b5 = (const float*)d_in[11];
    const float* lw = (const float*)d_in[12];
    const float* lb = (const float*)d_in[13];
    const float* w6 = (const float*)d_in[14];
    const float* b6 = (const float*)d_in[15];
    float* out = (float*)d_out;

    char* base = (char*)d_ws;
    size_t off = 0;
    auto alloc = [&](size_t bytes) -> char* {
        char* p = base + off;
        off += (bytes + 255) & ~(size_t)255;
        return p;
    };

    __hip_bfloat16* ZP = (__hip_bfloat16*)alloc(256);
    __hip_bfloat16* XF = (__hip_bfloat16*)alloc((size_t)BATCH * TPX * 96 * 2);
    __hip_bfloat16* Y1 = (__hip_bfloat16*)alloc((size_t)BATCH * TP * 128 * 2);
    __hip_bfloat16* P5 = (__hip_bfloat16*)alloc((size_t)BATCH * WHALO * DHALO * 128 * 2);
    float* XEp = (float*)alloc((size_t)BATCH * 128 * 64 * 2 * 4);
    __hip_bfloat16* WF1 = (__hip_bfloat16*)alloc((size_t)3 * 5 * 8 * 512 * 2);
    __hip_bfloat16* WF2 = (__hip_bfloat16*)alloc((size_t)4 * 5 * 8 * 512 * 2);
    __hip_bfloat16* WF3 = (__hip_bfloat16*)alloc((size_t)4 * 5 * 8 * 512 * 2);
    __hip_bfloat16* WF4 = (__hip_bfloat16*)alloc((size_t)4 * 25 * 8 * 512 * 2);
    __hip_bfloat16* WF5 = (__hip_bfloat16*)alloc((size_t)4 * 25 * 8 * 512 * 2);

    hipMemsetAsync(ZP, 0, 256, stream);

    zero_xf_halo_kernel<<<dim3(24, 32), 96, 0, stream>>>(XF);
    zero_p5_halo_kernel<<<14080, 256, 0, stream>>>(P5);

    pack_w_kernel<80, 3, 5><<<240, 256, 0, stream>>>(w1, WF1);
    pack_w_kernel<128, 4, 5><<<320, 256, 0, stream>>>(w2, WF2);
    pack_w_kernel<128, 4, 5><<<320, 256, 0, stream>>>(w3, WF3);
    pack_w_kernel<128, 4, 25><<<1600, 256, 0, stream>>>(w4, WF4);
    pack_w_kernel<128, 4, 25><<<1600, 256, 0, stream>>>(w5, WF5);

    cast_feat_kernel<<<dim3(64, 32), 256, 0, stream>>>(features, XF);

    // fused conv1d x3: XF -> emb (Y1)
    conv1d_fused_kernel<<<dim3(64, 32), 256, 0, stream>>>(XF, WF1, b1, WF2, b2, WF3, b3, Y1);

    // conv4: gather fused into DMA staging; emb -> P5 (halo plane)
    conv2d_lds_kernel<true, true, 1><<<dim3(32, 32), 512, 0, stream>>>(Y1, wbnd, WF4, b4, ZP,
                                                                       nullptr, nullptr, P5);

    // conv5 + fused einsum: P5 -> XEp fp32 partials
    conv2d_lds_kernel<false, true, 2><<<dim3(32, 32), 512, 0, stream>>>(P5, wbnd, WF5, b5, ZP,
                                                                        lw, XEp, nullptr);

    conv6_kernel<<<32, 256, 0, stream>>>(XEp, lb, w6, b6, out);
}

// Round 26
// 411.374 us; speedup vs baseline: 1.2400x; 1.2400x over previous
//
#include <hip/hip_runtime.h>
#include <hip/hip_bf16.h>
#include <cstdint>
#include <cstddef>

#define T_LEN 4096
#define TP 4104      // emb rows: pixel t at row t+2; rows 0,1 and 4098..4103 zero
#define TPX 4120     // XF rows: pixel t at row t+10; rows 0..9 and 4106..4119 zero
#define BATCH 32
#define NMELS 80
#define HID 128
#define W_WORDS 64
#define D_MAX 100
#define WHALO 68
#define DHALO 120

typedef __attribute__((ext_vector_type(4))) float f32x4;
typedef __attribute__((ext_vector_type(8))) short short8;

static __device__ __forceinline__ unsigned short f2bf(float f) {
    __hip_bfloat16 h = __float2bfloat16(f);
    return *reinterpret_cast<unsigned short*>(&h);
}

// async global->LDS DMA, 16B per lane; dest = wave-uniform base + lane*16
typedef const __attribute__((address_space(1))) unsigned int* as1_u32p;
typedef __attribute__((address_space(3))) unsigned int* as3_u32p;
static __device__ __forceinline__ void gload16(const void* g, void* l) {
    __builtin_amdgcn_global_load_lds((as1_u32p)(uintptr_t)g, (as3_u32p)(uintptr_t)l, 16, 0, 0);
}

// ---------- pack weights into MFMA A-fragment order ----------
template <int CIN, int CC, int TAPS>
__global__ __launch_bounds__(256) void pack_w_kernel(const float* __restrict__ w,
                                                     __hip_bfloat16* __restrict__ wf) {
    int idx = blockIdx.x * 256 + threadIdx.x;
    int r = idx;
    int j = r & 7; r >>= 3;
    int lane = r & 63; r >>= 6;
    int mi = r & 7; r >>= 3;
    int tap = r % TAPS;
    int cc = r / TAPS;
    if (cc >= CC) return;
    int co = mi * 16 + (lane & 15);
    int ci = cc * 32 + (lane >> 4) * 8 + j;
    float v = (ci < CIN) ? w[(co * CIN + ci) * TAPS + tap] : 0.f;
    wf[idx] = __float2bfloat16(v);
}

// ---------- cast features: tiled LDS transpose (b,80,t) fp32 -> XF (b,TPX,96) bf16 ----------
__global__ __launch_bounds__(256) void cast_feat_kernel(const float* __restrict__ f,
                                                        __hip_bfloat16* __restrict__ xf) {
    __shared__ unsigned short lds[64 * 100];
    const int tid = threadIdx.x;
    const int t0 = blockIdx.x * 64;
    const int b = blockIdx.y;

#pragma unroll
    for (int k = 0; k < 6; k++) {
        int idx = tid + k * 256;
        int f4 = idx & 15;
        int c = idx >> 4;
        float4 v = make_float4(0.f, 0.f, 0.f, 0.f);
        if (c < NMELS)
            v = *(const float4*)(f + ((size_t)b * NMELS + c) * T_LEN + t0 + f4 * 4);
        lds[(f4 * 4 + 0) * 100 + c] = f2bf(v.x);
        lds[(f4 * 4 + 1) * 100 + c] = f2bf(v.y);
        lds[(f4 * 4 + 2) * 100 + c] = f2bf(v.z);
        lds[(f4 * 4 + 3) * 100 + c] = f2bf(v.w);
    }
    __syncthreads();
    unsigned short* xp = (unsigned short*)xf;
#pragma unroll
    for (int k = 0; k < 6; k++) {
        int idx = tid + k * 256;
        int tl = idx / 24;
        int cq = idx - tl * 24;
        ushort4 o;
        o.x = lds[tl * 100 + cq * 4 + 0];
        o.y = lds[tl * 100 + cq * 4 + 1];
        o.z = lds[tl * 100 + cq * 4 + 2];
        o.w = lds[tl * 100 + cq * 4 + 3];
        *(ushort4*)(xp + ((size_t)b * TPX + t0 + tl + 10) * 96 + cq * 4) = o;
    }
}

// ---------- zero the 24 halo t-rows of XF (rows 0..9 and 4106..4119) ----------
__global__ void zero_xf_halo_kernel(__hip_bfloat16* __restrict__ p) {
    int r = blockIdx.x;            // 0..23
    int b = blockIdx.y;
    int row = (r < 10) ? r : 4096 + r; // 0..9, 4106..4119
    ((unsigned short*)p)[((size_t)b * TPX + row) * 96 + threadIdx.x] = 0;
}

// ---------- zero halo strips of P5 (b,68,120,128) ----------
__global__ __launch_bounds__(256) void zero_p5_halo_kernel(__hip_bfloat16* __restrict__ p) {
    int idx = blockIdx.x * 256 + threadIdx.x; // 32*1760*64
    if (idx >= 32 * 1760 * 64) return;
    int c2 = (idx & 63) * 2;
    int cell = idx >> 6;
    int b = cell / 1760;
    int cl = cell - b * 1760;
    int row, col;
    if (cl < 480) {
        int rr = cl / 120;
        row = (rr < 2) ? rr : 64 + rr;
        col = cl - rr * 120;
    } else {
        int cl2 = cl - 480;
        row = 2 + cl2 / 20;
        int q = cl2 % 20;
        col = (q < 2) ? q : 100 + q;
    }
    *(unsigned int*)((unsigned short*)p + (((size_t)b * WHALO + row) * DHALO + col) * 128 + c2) = 0u;
}

// ---------- FUSED conv1d x3: XF -> (h1,h2 in LDS) -> emb (round-15 form, kept) ----------
__global__ __launch_bounds__(256, 3) void conv1d_fused_kernel(
    const __hip_bfloat16* __restrict__ xf, const __hip_bfloat16* __restrict__ wf1,
    const float* __restrict__ b1, const __hip_bfloat16* __restrict__ wf2,
    const float* __restrict__ b2, const __hip_bfloat16* __restrict__ wf3,
    const float* __restrict__ b3, __hip_bfloat16* __restrict__ emb) {
    __shared__ short lds[(1344 + 1344) * 8];
    short* A = lds;              // XF, then h2
    short* H1 = lds + 1344 * 8;  // h1
    const int tid = threadIdx.x;
    const int lane = tid & 63;
    const int wid = tid >> 6;    // co-quarter (32 co)
    const int pix0 = blockIdx.x * 64;
    const int b = blockIdx.y;

    const short* xfp = (const short*)xf;
#pragma unroll
    for (int it = 0; it < 4; it++) {
        int cbase = (it * 4 + wid) * 64;
        if (cbase < 1008) {
            int cell = cbase + lane;
            int jg = cell / 84;
            int col = cell - jg * 84;
            if (jg > 11) { jg = 11; col = 83; } // pad lanes: clamp SOURCE (dest = pad cell)
            const short* g = xfp + ((size_t)(b * TPX + pix0 + col)) * 96 + jg * 8;
            gload16(g, A + (size_t)cbase * 8);
        }
    }
    __syncthreads(); // drain DMA

    const short* w1p = (const short*)wf1;
    const short* w2p = (const short*)wf2;
    const short* w3p = (const short*)wf3;

    f32x4 acc[5][2];

    // ---- layer 1: XF(A) -> h1(H1), relu ----
#pragma unroll
    for (int n = 0; n < 5; n++)
#pragma unroll
        for (int mi = 0; mi < 2; mi++) acc[n][mi] = (f32x4)0.f;
#pragma unroll 1
    for (int cc = 0; cc < 3; cc++) {
#pragma unroll
        for (int th = 0; th < 5; th++) {
            const short* wptr = w1p + ((cc * 5 + th) * 8 + wid * 2) * 512 + lane * 8;
            short8 wfr0 = *(const short8*)wptr;
            short8 wfr1 = *(const short8*)(wptr + 512);
            short8 xfr[5];
#pragma unroll
            for (int n = 0; n < 5; n++)
                xfr[n] = *(const short8*)&A[((cc * 4 + (lane >> 4)) * 84 +
                                             (n * 16 + (lane & 15) + th)) * 8];
#pragma unroll
            for (int n = 0; n < 5; n++) {
                acc[n][0] = __builtin_amdgcn_mfma_f32_16x16x32_bf16(wfr0, xfr[n], acc[n][0], 0, 0, 0);
                acc[n][1] = __builtin_amdgcn_mfma_f32_16x16x32_bf16(wfr1, xfr[n], acc[n][1], 0, 0, 0);
            }
        }
    }
#pragma unroll
    for (int mi = 0; mi < 2; mi++) {
        const float4 bv = *(const float4*)(b1 + wid * 32 + mi * 16 + (lane >> 4) * 4);
        const int jgI = wid * 4 + mi * 2 + ((lane >> 4) >> 1);
#pragma unroll
        for (int n = 0; n < 5; n++) {
            f32x4 a = acc[n][mi];
            const int col = n * 16 + (lane & 15) + 2;
            const int px = pix0 + col - 10;
            const bool inseq = ((unsigned)px < (unsigned)T_LEN);
            ushort4 o;
            o.x = inseq ? f2bf(fmaxf(a[0] + bv.x, 0.f)) : (unsigned short)0;
            o.y = inseq ? f2bf(fmaxf(a[1] + bv.y, 0.f)) : (unsigned short)0;
            o.z = inseq ? f2bf(fmaxf(a[2] + bv.z, 0.f)) : (unsigned short)0;
            o.w = inseq ? f2bf(fmaxf(a[3] + bv.w, 0.f)) : (unsigned short)0;
            *(ushort4*)&H1[(jgI * 84 + col) * 8 + ((lane >> 4) & 1) * 4] = o;
        }
    }
    __syncthreads(); // h1 published; XF reads done (A reusable)

    // ---- layer 2: h1(H1) -> h2(A), relu ----
#pragma unroll
    for (int n = 0; n < 5; n++)
#pragma unroll
        for (int mi = 0; mi < 2; mi++) acc[n][mi] = (f32x4)0.f;
#pragma unroll 1
    for (int cc = 0; cc < 4; cc++) {
#pragma unroll
        for (int th = 0; th < 5; th++) {
            const short* wptr = w2p + ((cc * 5 + th) * 8 + wid * 2) * 512 + lane * 8;
            short8 wfr0 = *(const short8*)wptr;
            short8 wfr1 = *(const short8*)(wptr + 512);
            short8 xfr[5];
#pragma unroll
            for (int n = 0; n < 5; n++)
                xfr[n] = *(const short8*)&H1[((cc * 4 + (lane >> 4)) * 84 +
                                              (n * 16 + (lane & 15) + th)) * 8];
#pragma unroll
            for (int n = 0; n < 5; n++) {
                acc[n][0] = __builtin_amdgcn_mfma_f32_16x16x32_bf16(wfr0, xfr[n], acc[n][0], 0, 0, 0);
                acc[n][1] = __builtin_amdgcn_mfma_f32_16x16x32_bf16(wfr1, xfr[n], acc[n][1], 0, 0, 0);
            }
        }
    }
#pragma unroll
    for (int mi = 0; mi < 2; mi++) {
        const float4 bv = *(const float4*)(b2 + wid * 32 + mi * 16 + (lane >> 4) * 4);
        const int jgI = wid * 4 + mi * 2 + ((lane >> 4) >> 1);
#pragma unroll
        for (int n = 0; n < 5; n++) {
            f32x4 a = acc[n][mi];
            const int col = n * 16 + (lane & 15) + 2;
            const int px = pix0 + col - 10;
            const bool inseq = ((unsigned)px < (unsigned)T_LEN);
            ushort4 o;
            o.x = inseq ? f2bf(fmaxf(a[0] + bv.x, 0.f)) : (unsigned short)0;
            o.y = inseq ? f2bf(fmaxf(a[1] + bv.y, 0.f)) : (unsigned short)0;
            o.z = inseq ? f2bf(fmaxf(a[2] + bv.z, 0.f)) : (unsigned short)0;
            o.w = inseq ? f2bf(fmaxf(a[3] + bv.w, 0.f)) : (unsigned short)0;
            *(ushort4*)&A[(jgI * 84 + col) * 8 + ((lane >> 4) & 1) * 4] = o;
        }
    }
    __syncthreads(); // h2 published

    // ---- layer 3: h2(A) -> emb global (no relu), 4 frags (64 px exact) ----
#pragma unroll
    for (int n = 0; n < 4; n++)
#pragma unroll
        for (int mi = 0; mi < 2; mi++) acc[n][mi] = (f32x4)0.f;
#pragma unroll 1
    for (int cc = 0; cc < 4; cc++) {
#pragma unroll
        for (int th = 0; th < 5; th++) {
            const short* wptr = w3p + ((cc * 5 + th) * 8 + wid * 2) * 512 + lane * 8;
            short8 wfr0 = *(const short8*)wptr;
            short8 wfr1 = *(const short8*)(wptr + 512);
            short8 xfr[4];
#pragma unroll
            for (int n = 0; n < 4; n++)
                xfr[n] = *(const short8*)&A[((cc * 4 + (lane >> 4)) * 84 +
                                             (n * 16 + (lane & 15) + th + 8)) * 8];
#pragma unroll
            for (int n = 0; n < 4; n++) {
                acc[n][0] = __builtin_amdgcn_mfma_f32_16x16x32_bf16(wfr0, xfr[n], acc[n][0], 0, 0, 0);
                acc[n][1] = __builtin_amdgcn_mfma_f32_16x16x32_bf16(wfr1, xfr[n], acc[n][1], 0, 0, 0);
            }
        }
    }
    unsigned short* ep = (unsigned short*)emb;
#pragma unroll
    for (int mi = 0; mi < 2; mi++) {
        const float4 bv = *(const float4*)(b3 + wid * 32 + mi * 16 + (lane >> 4) * 4);
#pragma unroll
        for (int n = 0; n < 4; n++) {
            f32x4 a = acc[n][mi];
            ushort4 o;
            o.x = f2bf(a[0] + bv.x);
            o.y = f2bf(a[1] + bv.y);
            o.z = f2bf(a[2] + bv.z);
            o.w = f2bf(a[3] + bv.w);
            const int px = pix0 + n * 16 + (lane & 15);
            *(ushort4*)(ep + ((size_t)(b * TP + px + 2)) * 128 + wid * 32 + mi * 16 +
                        (lane >> 4) * 4) = o;
        }
    }
}

// ---------- conv2d MFMA: round-22/24 proven form (512 thr, cohalf split, 32-ci slab) ----------
// LDS [jg(4)][row(8)][col(68)] 16B cells; 2176 cells = 34 whole-wave transfers exact.
// 34.8 KB LDS; th loop unroll 1 (register-safe). GATHER: fused word-gather staging.
// OMODE 1: bf16 halo plane out. OMODE 2: fused einsum -> fp32 partials xep[b,co,w,2].
template <bool GATHER, bool RELU, int OMODE>
__global__ __launch_bounds__(512, 4) void conv2d_lds_kernel(const __hip_bfloat16* __restrict__ in,
                                                            const int* __restrict__ wb,
                                                            const __hip_bfloat16* __restrict__ wf,
                                                            const float* __restrict__ bias,
                                                            const __hip_bfloat16* __restrict__ zp,
                                                            const float* __restrict__ lw,
                                                            float* __restrict__ xep,
                                                            __hip_bfloat16* __restrict__ outp) {
    __shared__ short lds[4 * 8 * 68 * 8]; // 34,816 B; 2176 cells = 34*64 exact
    __shared__ int2 s_sd[8];
    const int tid = threadIdx.x;
    const int lane = tid & 63;
    const int wid = tid >> 6;
    const int wrow = wid & 3;
    const int cohalf = wid >> 2;
    const int w0 = (blockIdx.x & 15) * 4;
    const int dtile = blockIdx.x >> 4;
    const int D0 = dtile * 64;
    const int ntlim = dtile ? 3 : 4;
    const int b = blockIdx.y;
    const int w = w0 + wrow;

    if (GATHER && tid < 8) {
        int wg = w0 + tid - 2;
        int s = 0, du = 0;
        if (wg >= 0 && wg < 64) {
            s = wb[(b * 64 + wg) * 2];
            du = wb[(b * 64 + wg) * 2 + 1] - s;
            if (du > D_MAX) du = D_MAX;
        }
        s_sd[tid] = make_int2(s, du);
    }
    __syncthreads(); // s_sd visible before staging

    const short* inp = (const short*)in;
    const short* wfp = (const short*)wf;

    auto stage = [&](int cc) {
#pragma unroll
        for (int it = 0; it < 5; it++) {
            int cbase = (it * 8 + wid) * 64;
            if (cbase < 2176) {
                int cell = cbase + lane;
                int jg = cell / 544;
                int rem = cell - jg * 544;
                int row = rem / 68;
                int col = rem - row * 68;
                const short* g;
                if (GATHER) {
                    int d = D0 + col - 2;
                    int2 sd = s_sd[row];
                    if ((unsigned)d < (unsigned)sd.y)
                        g = inp + ((size_t)(b * TP + 2 + sd.x + d)) * 128 + cc * 32 + jg * 8;
                    else
                        g = (const short*)zp;
                } else {
                    g = inp + ((size_t)((b * WHALO + w0 + row) * DHALO + D0 + col)) * 128 +
                        cc * 32 + jg * 8;
                }
                gload16(g, &lds[0] + (size_t)cbase * 8);
            }
        }
    };

    f32x4 acc[4][4];
#pragma unroll
    for (int n = 0; n < 4; n++)
#pragma unroll
        for (int mi = 0; mi < 4; mi++) acc[n][mi] = (f32x4)0.f;

#pragma unroll 1
    for (int cc = 0; cc < 4; cc++) {
        if (cc) __syncthreads();
        stage(cc);
        __syncthreads();
#pragma unroll 1
        for (int th = 0; th < 5; th++) {
#pragma unroll
            for (int tw = 0; tw < 5; tw++) {
                const int tap = th * 5 + tw;
                const short* wptr = wfp + ((cc * 25 + tap) * 8 + cohalf * 4) * 512 + lane * 8;
                short8 wfr[4];
#pragma unroll
                for (int mi = 0; mi < 4; mi++) wfr[mi] = *(const short8*)(wptr + mi * 512);

                short8 xfr[4];
#pragma unroll
                for (int n = 0; n < 4; n++)
                    if (n < ntlim)
                        xfr[n] = *(const short8*)&lds[(((lane >> 4) * 8 + wrow + th) * 68 +
                                                       (tw + n * 16 + (lane & 15))) * 8];

#pragma unroll
                for (int n = 0; n < 4; n++)
                    if (n < ntlim)
#pragma unroll
                        for (int mi = 0; mi < 4; mi++)
                            acc[n][mi] = __builtin_amdgcn_mfma_f32_16x16x32_bf16(
                                wfr[mi], xfr[n], acc[n][mi], 0, 0, 0);
            }
        }
    }

    if (OMODE == 1) {
        const int out_base = ((b * WHALO + w + 2) * DHALO + D0 + 2) * 128;
        unsigned short* outp16 = (unsigned short*)outp;
#pragma unroll
        for (int mi = 0; mi < 4; mi++) {
            const float4 bv = *(const float4*)(bias + cohalf * 64 + mi * 16 + (lane >> 4) * 4);
#pragma unroll
            for (int n = 0; n < 4; n++) {
                const int pix = n * 16 + (lane & 15);
                if (D0 + pix >= 100) continue;
                f32x4 a = acc[n][mi];
                float v0 = a[0] + bv.x, v1 = a[1] + bv.y, v2 = a[2] + bv.z, v3 = a[3] + bv.w;
                if (RELU) {
                    v0 = fmaxf(v0, 0.f); v1 = fmaxf(v1, 0.f);
                    v2 = fmaxf(v2, 0.f); v3 = fmaxf(v3, 0.f);
                }
                ushort4 o;
                o.x = f2bf(v0); o.y = f2bf(v1); o.z = f2bf(v2); o.w = f2bf(v3);
                *(ushort4*)(outp16 + out_base + pix * 128 + cohalf * 64 + mi * 16 +
                            (lane >> 4) * 4) = o;
            }
        }
    } else {
        float e[4][4];
#pragma unroll
        for (int mi = 0; mi < 4; mi++)
#pragma unroll
            for (int j = 0; j < 4; j++) e[mi][j] = 0.f;

#pragma unroll
        for (int mi = 0; mi < 4; mi++) {
            const float4 bv = *(const float4*)(bias + cohalf * 64 + mi * 16 + (lane >> 4) * 4);
#pragma unroll
            for (int n = 0; n < 4; n++) {
                const int pix = n * 16 + (lane & 15);
                if (D0 + pix >= 100) continue;
                const float lwv = lw[D0 + pix];
                f32x4 a = acc[n][mi];
                e[mi][0] += fmaxf(a[0] + bv.x, 0.f) * lwv;
                e[mi][1] += fmaxf(a[1] + bv.y, 0.f) * lwv;
                e[mi][2] += fmaxf(a[2] + bv.z, 0.f) * lwv;
                e[mi][3] += fmaxf(a[3] + bv.w, 0.f) * lwv;
            }
        }
#pragma unroll
        for (int mi = 0; mi < 4; mi++)
#pragma unroll
            for (int j = 0; j < 4; j++) {
                float v = e[mi][j];
                v += __shfl_xor(v, 1);
                v += __shfl_xor(v, 2);
                v += __shfl_xor(v, 4);
                v += __shfl_xor(v, 8);
                e[mi][j] = v;
            }
        if ((lane & 15) == 0) {
#pragma unroll
            for (int mi = 0; mi < 4; mi++)
#pragma unroll
                for (int j = 0; j < 4; j++) {
                    int co = cohalf * 64 + mi * 16 + (lane >> 4) * 4 + j;
                    xep[(((size_t)b * 128 + co) * 64 + w) * 2 + dtile] = e[mi][j];
                }
        }
    }
}

// ---------- final conv: XEp partials (b,128,64,2) -> out (b,64); ci-parallel ----------
__global__ __launch_bounds__(256) void conv6_kernel(const float* __restrict__ xep,
                                                    const float* __restrict__ lb,
                                                    const float* __restrict__ w6,
                                                    const float* __restrict__ b6,
                                                    float* __restrict__ out) {
    __shared__ float red[256];
    const int b = blockIdx.x;
    const int w = threadIdx.x & 63;
    const int cq = threadIdx.x >> 6; // 4 groups of 32 ci
    const float lb0 = lb[0];
    float partial = 0.f;
#pragma unroll 1
    for (int ci = cq * 32; ci < cq * 32 + 32; ci++) {
        const float* xr = xep + (((size_t)b * 128 + ci) * 64) * 2;
#pragma unroll
        for (int kh = 0; kh < 5; kh++) {
            int ww = w + kh - 2;
            if ((unsigned)ww < 64u) {
                float x = fmaxf(xr[ww * 2] + xr[ww * 2 + 1] + lb0, 0.f);
                partial += x * w6[ci * 25 + kh * 5 + 2];
            }
        }
    }
    red[threadIdx.x] = partial;
    __syncthreads();
    if (cq == 0)
        out[b * 64 + w] = red[w] + red[w + 64] + red[w + 128] + red[w + 192] + b6[0];
}

extern "C" void kernel_launch(void* const* d_in, const int* in_sizes, int n_in,
                              void* d_out, int out_size, void* d_ws, size_t ws_size,
                              hipStream_t stream) {
    const float* features = (const float*)d_in[0];
    const int* wbnd = (const int*)d_in[1];
    const float* w1 = (const float*)d_in[2];
    const float* b1 = (const float*)d_in[3];
    const float* w2 = (const float*)d_in[4];
    const float* b2 = (const float*)d_in[5];
    const float* w3 = (const float*)d_in[6];
    const float* b3 = (const float*)d_in[7];
    const float* w4 = (const float*)d_in[8];
    const float* b4 = (const float*)d_in[9];
    const float* w5 = (const float*)d_in[10];
    const float* b5 = (const float*)d_in[11];
    const float* lw = (const float*)d_in[12];
    const float* lb = (const float*)d_in[13];
    const float* w6 = (const float*)d_in[14];
    const float* b6 = (const float*)d_in[15];
    float* out = (float*)d_out;

    char* base = (char*)d_ws;
    size_t off = 0;
    auto alloc = [&](size_t bytes) -> char* {
        char* p = base + off;
        off += (bytes + 255) & ~(size_t)255;
        return p;
    };

    __hip_bfloat16* ZP = (__hip_bfloat16*)alloc(256);
    __hip_bfloat16* XF = (__hip_bfloat16*)alloc((size_t)BATCH * TPX * 96 * 2);
    __hip_bfloat16* Y1 = (__hip_bfloat16*)alloc((size_t)BATCH * TP * 128 * 2);
    __hip_bfloat16* P5 = (__hip_bfloat16*)alloc((size_t)BATCH * WHALO * DHALO * 128 * 2);
    float* XEp = (float*)alloc((size_t)BATCH * 128 * 64 * 2 * 4);
    __hip_bfloat16* WF1 = (__hip_bfloat16*)alloc((size_t)3 * 5 * 8 * 512 * 2);
    __hip_bfloat16* WF2 = (__hip_bfloat16*)alloc((size_t)4 * 5 * 8 * 512 * 2);
    __hip_bfloat16* WF3 = (__hip_bfloat16*)alloc((size_t)4 * 5 * 8 * 512 * 2);
    __hip_bfloat16* WF4 = (__hip_bfloat16*)alloc((size_t)4 * 25 * 8 * 512 * 2);
    __hip_bfloat16* WF5 = (__hip_bfloat16*)alloc((size_t)4 * 25 * 8 * 512 * 2);

    hipMemsetAsync(ZP, 0, 256, stream);

    zero_xf_halo_kernel<<<dim3(24, 32), 96, 0, stream>>>(XF);
    zero_p5_halo_kernel<<<14080, 256, 0, stream>>>(P5);

    pack_w_kernel<80, 3, 5><<<240, 256, 0, stream>>>(w1, WF1);
    pack_w_kernel<128, 4, 5><<<320, 256, 0, stream>>>(w2, WF2);
    pack_w_kernel<128, 4, 5><<<320, 256, 0, stream>>>(w3, WF3);
    pack_w_kernel<128, 4, 25><<<1600, 256, 0, stream>>>(w4, WF4);
    pack_w_kernel<128, 4, 25><<<1600, 256, 0, stream>>>(w5, WF5);

    cast_feat_kernel<<<dim3(64, 32), 256, 0, stream>>>(features, XF);

    // fused conv1d x3: XF -> emb (Y1)
    conv1d_fused_kernel<<<dim3(64, 32), 256, 0, stream>>>(XF, WF1, b1, WF2, b2, WF3, b3, Y1);

    // conv4: gather fused into DMA staging; emb -> P5 (halo plane)
    conv2d_lds_kernel<true, true, 1><<<dim3(32, 32), 512, 0, stream>>>(Y1, wbnd, WF4, b4, ZP,
                                                                       nullptr, nullptr, P5);

    // conv5 + fused einsum: P5 -> XEp fp32 partials
    conv2d_lds_kernel<false, true, 2><<<dim3(32, 32), 512, 0, stream>>>(P5, wbnd, WF5, b5, ZP,
                                                                        lw, XEp, nullptr);

    conv6_kernel<<<32, 256, 0, stream>>>(XEp, lb, w6, b6, out);
}